// Round 2
// baseline (17750.520 us; speedup 1.0000x reference)
//
#include <hip/hip_runtime.h>
#include <cstdint>
#include <cstddef>

typedef __bf16 bf16;
typedef __bf16 bf16x8 __attribute__((ext_vector_type(8)));
typedef __bf16 bf16x4 __attribute__((ext_vector_type(4)));
typedef float f32x4 __attribute__((ext_vector_type(4)));

#define B_ 64
#define S_ 512
#define E_ 512
#define H_ 1024
#define C_ 20
#define EH 1536   // E+H
#define G4 4096   // 4*H

// ---- workspace layout (bytes) ----
static const size_t OFF_WCAT  = 0;              // bf16 [4096][1536] = 12,582,912
static const size_t OFF_BIAS4 = 12582912;       // f32  [4096]       = 16,384
static const size_t OFF_A0    = 12599296;       // bf16 [64][1024]   = 131,072
static const size_t OFF_A1    = 12730368;       // bf16 [64][1024]   = 131,072
static const size_t OFF_CST   = 12861440;       // f32  [64][1024]   = 262,144
static const size_t OFF_LOSS  = 13123584;       // f32  [64]         = 256
static const size_t OFF_BAR   = 13123840;       // u32  [256]        = 1,024
static const size_t OFF_GX    = 13124864;       // bf16 [TC*64][4096] = TC*524,288
static const size_t STATE_BYTES = OFF_GX - OFF_A0;   // 525,568 (zeroed each call)

__device__ inline float sigmoidf_(float x) { return 1.0f / (1.0f + __expf(-x)); }
__device__ inline float tanh_fast(float x) {
  float ax = fabsf(x);
  float e = __expf(-2.0f * ax);
  float t = (1.0f - e) / (1.0f + e);
  return copysignf(t, x);
}

// ---- zero a0/a1/cst/loss/bar (state region is contiguous) ----
__global__ __launch_bounds__(256) void init_misc(uint4* st) {
  const int n = (int)(STATE_BYTES / 16);   // 32,848
  for (int idx = blockIdx.x * 256 + threadIdx.x; idx < n; idx += gridDim.x * 256)
    st[idx] = uint4{0u, 0u, 0u, 0u};
}

// ---- convert gate weights to bf16, rows r = h*4+g (h-major, gate minor) ----
__global__ __launch_bounds__(256) void convert_w(
    const float* __restrict__ Wf, const float* __restrict__ Wi,
    const float* __restrict__ Wc, const float* __restrict__ Wo,
    const float* __restrict__ bfp, const float* __restrict__ bip,
    const float* __restrict__ bcp, const float* __restrict__ bop,
    bf16* __restrict__ Wcat, float* __restrict__ bias4)
{
  const int total = G4 * (EH / 8);   // 786,432 chunks of 8
  for (int idx = blockIdx.x * 256 + threadIdx.x; idx < total; idx += gridDim.x * 256) {
    const int r = idx / 192;
    const int ck = idx - r * 192;
    const int g = r & 3, h = r >> 2;
    const float* W = (g == 0) ? Wf : (g == 1) ? Wi : (g == 2) ? Wc : Wo;
    const float* src = W + (size_t)h * EH + ck * 8;
    const float4 v0 = *(const float4*)src;
    const float4 v1 = *(const float4*)(src + 4);
    bf16x8 o;
    o[0] = (bf16)v0.x; o[1] = (bf16)v0.y; o[2] = (bf16)v0.z; o[3] = (bf16)v0.w;
    o[4] = (bf16)v1.x; o[5] = (bf16)v1.y; o[6] = (bf16)v1.z; o[7] = (bf16)v1.w;
    *(bf16x8*)(Wcat + (size_t)r * EH + ck * 8) = o;
    if (ck == 0) {
      const float* Bp = (g == 0) ? bfp : (g == 1) ? bip : (g == 2) ? bcp : bop;
      bias4[r] = Bp[h];
    }
  }
}

// ---- gx_chunk[ml][r] = sum_k emb[x[m]][k] * Wcat[r][k], K = 512 (x-part) ----
// m = t*64 + b (global), ml = m - t0*64. 128x128 tile, 4 waves, XOR-swizzled LDS.
// Embedding gather fused into the A-tile stage (f32 -> bf16 on the fly).
__global__ __launch_bounds__(256) void gemm_gx(
    const int* __restrict__ x, const float* __restrict__ emb,
    const bf16* __restrict__ Wcat, bf16* __restrict__ gx, int t0)
{
  __shared__ char As[16384];
  __shared__ char Bs[16384];
  const int t = threadIdx.x;
  const int lane = t & 63, wid = t >> 6;
  const int wm = wid >> 1, wn = wid & 1;
  const int bm = blockIdx.x >> 5;
  const int bn = blockIdx.x & 31;
  const int m0l = bm * 128, n0 = bn * 128;
  f32x4 acc[4][4] = {};
  const int srow = t >> 3, sc16 = t & 7;
  for (int k0 = 0; k0 < E_; k0 += 64) {
    __syncthreads();
    #pragma unroll
    for (int i = 0; i < 4; ++i) {
      const int row = i * 32 + srow;
      const int cs = sc16 ^ (row & 7);     // pre-swizzled source chunk
      // A: embedding row for global m = t0*64 + m0l + row
      const int m = t0 * 64 + m0l + row;
      const int tok = x[(m & 63) * S_ + (m >> 6)];
      const float* srcA = emb + (size_t)tok * E_ + k0 + cs * 8;
      const float4 a0v = *(const float4*)srcA;
      const float4 a1v = *(const float4*)(srcA + 4);
      bf16x8 oa;
      oa[0] = (bf16)a0v.x; oa[1] = (bf16)a0v.y; oa[2] = (bf16)a0v.z; oa[3] = (bf16)a0v.w;
      oa[4] = (bf16)a1v.x; oa[5] = (bf16)a1v.y; oa[6] = (bf16)a1v.z; oa[7] = (bf16)a1v.w;
      *(bf16x8*)(As + row * 128 + sc16 * 16) = oa;
      const uint4 vb = *(const uint4*)(Wcat + (size_t)(n0 + row) * EH + k0 + cs * 8);
      *(uint4*)(Bs + row * 128 + sc16 * 16) = vb;
    }
    __syncthreads();
    #pragma unroll
    for (int ks = 0; ks < 64; ks += 32) {
      const int kb = (ks + ((lane >> 4) * 8)) * 2;
      bf16x8 af[4], bfr[4];
      #pragma unroll
      for (int mt = 0; mt < 4; ++mt) {
        const int ra = wm * 64 + mt * 16 + (lane & 15);
        af[mt] = *(const bf16x8*)(As + ra * 128 + (kb ^ ((ra & 7) << 4)));
      }
      #pragma unroll
      for (int nt = 0; nt < 4; ++nt) {
        const int rb = wn * 64 + nt * 16 + (lane & 15);
        bfr[nt] = *(const bf16x8*)(Bs + rb * 128 + (kb ^ ((rb & 7) << 4)));
      }
      #pragma unroll
      for (int mt = 0; mt < 4; ++mt)
        #pragma unroll
        for (int nt = 0; nt < 4; ++nt)
          acc[mt][nt] = __builtin_amdgcn_mfma_f32_16x16x32_bf16(af[mt], bfr[nt], acc[mt][nt], 0, 0, 0);
    }
  }
  const int cb = (lane >> 4) * 4;
  #pragma unroll
  for (int mt = 0; mt < 4; ++mt) {
    #pragma unroll
    for (int r = 0; r < 4; ++r) {
      const int mrow = m0l + wm * 64 + mt * 16 + cb + r;   // chunk-local row
      bf16* dst = gx + (size_t)mrow * G4 + n0 + wn * 64 + (lane & 15);
      #pragma unroll
      for (int nt = 0; nt < 4; ++nt)
        dst[nt * 16] = (bf16)acc[mt][nt][r];
    }
  }
}

// ---- persistent LSTM recurrence over steps [t0, t0+tc) ----
// 128 WGs = 2 batch-groups (32 batches) x 64 hidden-slice WGs (16 h each).
// W slice [64 gate-rows][1024] bf16 in LDS (swizzled); c-state in regs,
// persisted to ws across chunk launches. Per step: MFMA [32x64] +=
// a_prev[32x1024] * Wslice^T; gates; write a_next slice; 64-WG device barrier
// keyed on the GLOBAL step number (monotone across chunk launches).
#define REC_LDS (131072 + 8192)

__global__ __launch_bounds__(256, 1) void lstm_rec(
    const bf16* __restrict__ Wcat, const float* __restrict__ bias4,
    const bf16* __restrict__ gx, bf16* __restrict__ a0,
    bf16* __restrict__ a1, float* __restrict__ cstg,
    unsigned* __restrict__ bar, int t0, int tc)
{
  extern __shared__ char smem[];
  char* Ws = smem;                          // [64][1024] bf16 swizzled
  float* accs = (float*)(smem + 131072);    // [32][64] f32
  const int t = threadIdx.x;
  const int lane = t & 63;
  const int wid = t >> 6;
  const int bid = blockIdx.x;
  const int grp = bid & 1;                  // batch group (32 batches)
  const int hwg = bid >> 1;                 // 0..63 hidden slice
  const int h0 = hwg * 16;

  // stage W rows [h0*4, h0*4+64), cols [512,1536) into LDS (swizzled)
  for (int i = 0; i < 32; ++i) {
    const int chunk = i * 256 + t;          // 0..8191
    const int row = chunk >> 7;
    const int c16 = chunk & 127;
    const uint4 v = *(const uint4*)(Wcat + (size_t)(h0 * 4 + row) * EH + 512 + c16 * 8);
    *(uint4*)(Ws + row * 2048 + ((c16 * 16) ^ ((row & 7) << 4))) = v;
  }
  const int bl = t >> 4;                    // 0..15
  const int j  = t & 15;                    // hidden unit within slice
  const float4 bias = *(const float4*)(bias4 + (h0 + j) * 4);
  const int bg0 = grp * 32 + bl;
  const int bg1 = bg0 + 16;
  float cst0 = cstg[(size_t)bg0 * H_ + h0 + j];
  float cst1 = cstg[(size_t)bg1 * H_ + h0 + j];
  unsigned* cnt = bar + grp * 64;
  unsigned* flg = bar + grp * 64 + 32;
  const int rb = wid * 16 + (lane & 15);
  const char* wrow = Ws + rb * 2048;
  const int kq = (lane >> 4) * 8;
  const int swz = (rb & 7) << 4;
  __syncthreads();

  for (int s = 0; s < tc; ++s) {
    const int step = t0 + s;
    const bf16* aprev = (step & 1) ? a1 : a0;
    bf16* anext = (step & 1) ? a0 : a1;
    const bf16* gxrow = gx + (size_t)s * (B_ * G4);
    const bf16x4 g0 = *(const bf16x4*)(gxrow + (size_t)bg0 * G4 + (h0 + j) * 4);
    const bf16x4 g1 = *(const bf16x4*)(gxrow + (size_t)bg1 * G4 + (h0 + j) * 4);

    f32x4 acc0 = {0.f, 0.f, 0.f, 0.f}, acc1 = {0.f, 0.f, 0.f, 0.f};
    const bf16* ap0 = aprev + (size_t)(grp * 32 + (lane & 15)) * H_ + kq;
    const bf16* ap1 = ap0 + (size_t)16 * H_;
    #pragma unroll 4
    for (int k0 = 0; k0 < H_; k0 += 32) {
      const bf16x8 bfr = *(const bf16x8*)(wrow + (((k0 + kq) * 2) ^ swz));
      const bf16x8 af0 = *(const bf16x8*)(ap0 + k0);
      const bf16x8 af1 = *(const bf16x8*)(ap1 + k0);
      acc0 = __builtin_amdgcn_mfma_f32_16x16x32_bf16(af0, bfr, acc0, 0, 0, 0);
      acc1 = __builtin_amdgcn_mfma_f32_16x16x32_bf16(af1, bfr, acc1, 0, 0, 0);
    }
    {
      const int col = wid * 16 + (lane & 15);
      const int brow = (lane >> 4) * 4;
      #pragma unroll
      for (int r = 0; r < 4; ++r) {
        accs[(brow + r) * 64 + col]      = acc0[r];
        accs[(brow + r + 16) * 64 + col] = acc1[r];
      }
    }
    __syncthreads();
    const float4 p0 = *(const float4*)(accs + bl * 64 + j * 4);
    const float4 p1 = *(const float4*)(accs + (bl + 16) * 64 + j * 4);
    {
      const float pf = p0.x + (float)g0[0] + bias.x;
      const float pi = p0.y + (float)g0[1] + bias.y;
      const float pc = p0.z + (float)g0[2] + bias.z;
      const float po = p0.w + (float)g0[3] + bias.w;
      const float fg = sigmoidf_(pf), ig = sigmoidf_(pi), og = sigmoidf_(po);
      cst0 = fg * cst0 + ig * tanh_fast(pc);
      anext[(size_t)bg0 * H_ + h0 + j] = (bf16)(tanh_fast(cst0) * og);
    }
    {
      const float pf = p1.x + (float)g1[0] + bias.x;
      const float pi = p1.y + (float)g1[1] + bias.y;
      const float pc = p1.z + (float)g1[2] + bias.z;
      const float po = p1.w + (float)g1[3] + bias.w;
      const float fg = sigmoidf_(pf), ig = sigmoidf_(pi), og = sigmoidf_(po);
      cst1 = fg * cst1 + ig * tanh_fast(pc);
      anext[(size_t)bg1 * H_ + h0 + j] = (bf16)(tanh_fast(cst1) * og);
    }
    __threadfence();
    __syncthreads();
    if (t == 0) {
      const unsigned old = __hip_atomic_fetch_add(cnt, 1u, __ATOMIC_ACQ_REL, __HIP_MEMORY_SCOPE_AGENT);
      if (old == 63u) {
        __hip_atomic_store(cnt, 0u, __ATOMIC_RELAXED, __HIP_MEMORY_SCOPE_AGENT);
        __hip_atomic_store(flg, (unsigned)(step + 1), __ATOMIC_RELEASE, __HIP_MEMORY_SCOPE_AGENT);
      } else {
        while (__hip_atomic_load(flg, __ATOMIC_ACQUIRE, __HIP_MEMORY_SCOPE_AGENT) < (unsigned)(step + 1)) {
          __builtin_amdgcn_s_sleep(2);
        }
      }
    }
    __syncthreads();
    __threadfence();
  }
  cstg[(size_t)bg0 * H_ + h0 + j] = cst0;
  cstg[(size_t)bg1 * H_ + h0 + j] = cst1;
}

// ---- logits + per-batch loss ----
__global__ __launch_bounds__(256) void logits_loss(
    const bf16* __restrict__ afin, const float* __restrict__ Wv,
    const float* __restrict__ bv, const int* __restrict__ label,
    float* __restrict__ lossa)
{
  const int b = blockIdx.x;
  const int t = threadIdx.x;
  const int lane = t & 63, wid = t >> 6;
  const bf16x4 a4 = *(const bf16x4*)(afin + (size_t)b * H_ + t * 4);
  const float av0 = (float)a4[0], av1 = (float)a4[1], av2 = (float)a4[2], av3 = (float)a4[3];
  float part[C_];
  #pragma unroll
  for (int c = 0; c < C_; ++c) {
    const float4 w = *(const float4*)(Wv + (size_t)c * H_ + t * 4);
    part[c] = av0 * w.x + av1 * w.y + av2 * w.z + av3 * w.w;
  }
  #pragma unroll
  for (int off = 32; off > 0; off >>= 1) {
    #pragma unroll
    for (int c = 0; c < C_; ++c) part[c] += __shfl_down(part[c], off);
  }
  __shared__ float red[4][C_];
  __shared__ float lg[C_];
  if (lane == 0) {
    #pragma unroll
    for (int c = 0; c < C_; ++c) red[wid][c] = part[c];
  }
  __syncthreads();
  if (t < C_) lg[t] = red[0][t] + red[1][t] + red[2][t] + red[3][t] + bv[t];
  __syncthreads();
  if (t == 0) {
    float m = lg[0];
    for (int c = 1; c < C_; ++c) m = fmaxf(m, lg[c]);
    float se = 0.0f;
    for (int c = 0; c < C_; ++c) se += __expf(lg[c] - m);
    const float lse = logf(se) + m;
    lossa[b] = lse - lg[label[b]];
  }
}

__global__ __launch_bounds__(64) void loss_mean(const float* __restrict__ lossa,
                                                float* __restrict__ out) {
  const int t = threadIdx.x;
  float v = lossa[t];
  #pragma unroll
  for (int off = 32; off > 0; off >>= 1) v += __shfl_down(v, off);
  if (t == 0) out[0] = v * (1.0f / 64.0f);
}

extern "C" void kernel_launch(void* const* d_in, const int* in_sizes, int n_in,
                              void* d_out, int out_size, void* d_ws, size_t ws_size,
                              hipStream_t stream) {
  const int*   x     = (const int*)d_in[0];
  const int*   label = (const int*)d_in[1];
  const float* emb   = (const float*)d_in[2];
  const float* Wf    = (const float*)d_in[3];
  const float* bfp   = (const float*)d_in[4];
  const float* Wi    = (const float*)d_in[5];
  const float* bip   = (const float*)d_in[6];
  const float* Wc    = (const float*)d_in[7];
  const float* bcp   = (const float*)d_in[8];
  const float* Wo    = (const float*)d_in[9];
  const float* bop   = (const float*)d_in[10];
  const float* Wv    = (const float*)d_in[11];
  const float* bv    = (const float*)d_in[12];
  (void)in_sizes; (void)n_in; (void)out_size;

  // Pick the largest time-chunk TC whose gx buffer fits the workspace.
  int TC = 0;
  const size_t avail = (ws_size > OFF_GX) ? (ws_size - OFF_GX) : 0;
  const int cands[7] = {512, 256, 128, 64, 32, 16, 8};
  for (int i = 0; i < 7; ++i) {
    if ((size_t)cands[i] * 524288 <= avail) { TC = cands[i]; break; }
  }
  if (TC == 0) return;   // ws < ~17.3 MB — cannot run this design

  char* ws = (char*)d_ws;
  bf16*     Wcat  = (bf16*)(ws + OFF_WCAT);
  float*    bias4 = (float*)(ws + OFF_BIAS4);
  bf16*     a0    = (bf16*)(ws + OFF_A0);
  bf16*     a1    = (bf16*)(ws + OFF_A1);
  float*    cstg  = (float*)(ws + OFF_CST);
  float*    lossa = (float*)(ws + OFF_LOSS);
  unsigned* bar   = (unsigned*)(ws + OFF_BAR);
  bf16*     gx    = (bf16*)(ws + OFF_GX);

  init_misc<<<64, 256, 0, stream>>>((uint4*)(ws + OFF_A0));
  convert_w<<<1024, 256, 0, stream>>>(Wf, Wi, Wc, Wo, bfp, bip, bcp, bop, Wcat, bias4);
  hipFuncSetAttribute(reinterpret_cast<const void*>(lstm_rec),
                      hipFuncAttributeMaxDynamicSharedMemorySize, REC_LDS);
  const int nchunks = S_ / TC;
  for (int c = 0; c < nchunks; ++c) {
    const int t0 = c * TC;
    gemm_gx<<<(TC / 2) * 32, 256, 0, stream>>>(x, emb, Wcat, gx, t0);
    lstm_rec<<<128, 256, REC_LDS, stream>>>(Wcat, bias4, gx, a0, a1, cstg, bar, t0, TC);
  }
  logits_loss<<<64, 256, 0, stream>>>(a0, Wv, bv, label, lossa);
  loss_mean<<<1, 64, 0, stream>>>(lossa, (float*)d_out);
}

// Round 3
// 7223.876 us; speedup vs baseline: 2.4572x; 2.4572x over previous
//
#include <hip/hip_runtime.h>
#include <cstdint>
#include <cstddef>

typedef __bf16 bf16;
typedef __bf16 bf16x8 __attribute__((ext_vector_type(8)));
typedef __bf16 bf16x4 __attribute__((ext_vector_type(4)));
typedef float f32x4 __attribute__((ext_vector_type(4)));

#define B_ 64
#define S_ 512
#define E_ 512
#define H_ 1024
#define C_ 20
#define EH 1536   // E+H
#define G4 4096   // 4*H

// ---- workspace layout (bytes) ----
static const size_t OFF_WCAT  = 0;              // bf16 [4096][1536] = 12,582,912
static const size_t OFF_BIAS4 = 12582912;       // f32  [4096]       = 16,384
static const size_t OFF_A0    = 12599296;       // bf16 [64][1024]   = 131,072
static const size_t OFF_A1    = 12730368;       // bf16 [64][1024]   = 131,072
static const size_t OFF_CST   = 12861440;       // f32  [64][1024]   = 262,144
static const size_t OFF_LOSS  = 13123584;       // f32  [64]         = 256
static const size_t OFF_BAR   = 13123840;       // u32  [256]        = 1,024
static const size_t OFF_GX    = 13124864;       // bf16 [TC*64][4096] = TC*524,288
static const size_t STATE_BYTES = OFF_GX - OFF_A0;   // 525,568 (zeroed each call)

__device__ inline float sigmoidf_(float x) { return 1.0f / (1.0f + __expf(-x)); }
__device__ inline float tanh_fast(float x) {
  float ax = fabsf(x);
  float e = __expf(-2.0f * ax);
  float t = (1.0f - e) / (1.0f + e);
  return copysignf(t, x);
}

// ---- zero a0/a1/cst/loss/bar (state region is contiguous) ----
__global__ __launch_bounds__(256) void init_misc(uint4* st) {
  const int n = (int)(STATE_BYTES / 16);   // 32,848
  for (int idx = blockIdx.x * 256 + threadIdx.x; idx < n; idx += gridDim.x * 256)
    st[idx] = uint4{0u, 0u, 0u, 0u};
}

// ---- convert gate weights to bf16, rows r = h*4+g (h-major, gate minor) ----
__global__ __launch_bounds__(256) void convert_w(
    const float* __restrict__ Wf, const float* __restrict__ Wi,
    const float* __restrict__ Wc, const float* __restrict__ Wo,
    const float* __restrict__ bfp, const float* __restrict__ bip,
    const float* __restrict__ bcp, const float* __restrict__ bop,
    bf16* __restrict__ Wcat, float* __restrict__ bias4)
{
  const int total = G4 * (EH / 8);   // 786,432 chunks of 8
  for (int idx = blockIdx.x * 256 + threadIdx.x; idx < total; idx += gridDim.x * 256) {
    const int r = idx / 192;
    const int ck = idx - r * 192;
    const int g = r & 3, h = r >> 2;
    const float* W = (g == 0) ? Wf : (g == 1) ? Wi : (g == 2) ? Wc : Wo;
    const float* src = W + (size_t)h * EH + ck * 8;
    const float4 v0 = *(const float4*)src;
    const float4 v1 = *(const float4*)(src + 4);
    bf16x8 o;
    o[0] = (bf16)v0.x; o[1] = (bf16)v0.y; o[2] = (bf16)v0.z; o[3] = (bf16)v0.w;
    o[4] = (bf16)v1.x; o[5] = (bf16)v1.y; o[6] = (bf16)v1.z; o[7] = (bf16)v1.w;
    *(bf16x8*)(Wcat + (size_t)r * EH + ck * 8) = o;
    if (ck == 0) {
      const float* Bp = (g == 0) ? bfp : (g == 1) ? bip : (g == 2) ? bcp : bop;
      bias4[r] = Bp[h];
    }
  }
}

// ---- gx_chunk[ml][r] = sum_k emb[x[m]][k] * Wcat[r][k], K = 512 (x-part) ----
// m = t*64 + b (global), ml = m - t0*64. 128x128 tile, 4 waves, XOR-swizzled LDS.
// Embedding gather fused into the A-tile stage (f32 -> bf16 on the fly).
__global__ __launch_bounds__(256) void gemm_gx(
    const int* __restrict__ x, const float* __restrict__ emb,
    const bf16* __restrict__ Wcat, bf16* __restrict__ gx, int t0)
{
  __shared__ char As[16384];
  __shared__ char Bs[16384];
  const int t = threadIdx.x;
  const int lane = t & 63, wid = t >> 6;
  const int wm = wid >> 1, wn = wid & 1;
  const int bm = blockIdx.x >> 5;
  const int bn = blockIdx.x & 31;
  const int m0l = bm * 128, n0 = bn * 128;
  f32x4 acc[4][4] = {};
  const int srow = t >> 3, sc16 = t & 7;
  for (int k0 = 0; k0 < E_; k0 += 64) {
    __syncthreads();
    #pragma unroll
    for (int i = 0; i < 4; ++i) {
      const int row = i * 32 + srow;
      const int cs = sc16 ^ (row & 7);     // pre-swizzled source chunk
      const int m = t0 * 64 + m0l + row;
      const int tok = x[(m & 63) * S_ + (m >> 6)];
      const float* srcA = emb + (size_t)tok * E_ + k0 + cs * 8;
      const float4 a0v = *(const float4*)srcA;
      const float4 a1v = *(const float4*)(srcA + 4);
      bf16x8 oa;
      oa[0] = (bf16)a0v.x; oa[1] = (bf16)a0v.y; oa[2] = (bf16)a0v.z; oa[3] = (bf16)a0v.w;
      oa[4] = (bf16)a1v.x; oa[5] = (bf16)a1v.y; oa[6] = (bf16)a1v.z; oa[7] = (bf16)a1v.w;
      *(bf16x8*)(As + row * 128 + sc16 * 16) = oa;
      const uint4 vb = *(const uint4*)(Wcat + (size_t)(n0 + row) * EH + k0 + cs * 8);
      *(uint4*)(Bs + row * 128 + sc16 * 16) = vb;
    }
    __syncthreads();
    #pragma unroll
    for (int ks = 0; ks < 64; ks += 32) {
      const int kb = (ks + ((lane >> 4) * 8)) * 2;
      bf16x8 af[4], bfr[4];
      #pragma unroll
      for (int mt = 0; mt < 4; ++mt) {
        const int ra = wm * 64 + mt * 16 + (lane & 15);
        af[mt] = *(const bf16x8*)(As + ra * 128 + (kb ^ ((ra & 7) << 4)));
      }
      #pragma unroll
      for (int nt = 0; nt < 4; ++nt) {
        const int rb = wn * 64 + nt * 16 + (lane & 15);
        bfr[nt] = *(const bf16x8*)(Bs + rb * 128 + (kb ^ ((rb & 7) << 4)));
      }
      #pragma unroll
      for (int mt = 0; mt < 4; ++mt)
        #pragma unroll
        for (int nt = 0; nt < 4; ++nt)
          acc[mt][nt] = __builtin_amdgcn_mfma_f32_16x16x32_bf16(af[mt], bfr[nt], acc[mt][nt], 0, 0, 0);
    }
  }
  const int cb = (lane >> 4) * 4;
  #pragma unroll
  for (int mt = 0; mt < 4; ++mt) {
    #pragma unroll
    for (int r = 0; r < 4; ++r) {
      const int mrow = m0l + wm * 64 + mt * 16 + cb + r;   // chunk-local row
      bf16* dst = gx + (size_t)mrow * G4 + n0 + wn * 64 + (lane & 15);
      #pragma unroll
      for (int nt = 0; nt < 4; ++nt)
        dst[nt * 16] = (bf16)acc[mt][nt][r];
    }
  }
}

// ---- persistent LSTM recurrence over steps [t0, t0+tc) ----
// 128 WGs = 2 batch-groups (32 batches) x 64 hidden-slice WGs (16 h each).
// Step barrier redesign (R2): a_next published via relaxed AGENT-scope 4B
// atomic stores (write-through to MALL); __syncthreads drains vmcnt; one
// relaxed flag store per WG; wave 0 polls all 64 flags in parallel (lane i
// spins on flags[i], relaxed loads, no RMW); single acquire fence
// (buffer_inv) so next step's plain a_prev loads can't hit stale L2.
#define REC_LDS (131072 + 8192)

__global__ __launch_bounds__(256, 1) void lstm_rec(
    const bf16* __restrict__ Wcat, const float* __restrict__ bias4,
    const bf16* __restrict__ gx, bf16* __restrict__ a0,
    bf16* __restrict__ a1, float* __restrict__ cstg,
    unsigned* __restrict__ bar, int t0, int tc)
{
  extern __shared__ char smem[];
  char* Ws = smem;                          // [64][1024] bf16 swizzled
  float* accs = (float*)(smem + 131072);    // [32][64] f32
  const int t = threadIdx.x;
  const int lane = t & 63;
  const int wid = t >> 6;
  const int bid = blockIdx.x;
  const int grp = bid & 1;                  // batch group (32 batches)
  const int hwg = bid >> 1;                 // 0..63 hidden slice
  const int h0 = hwg * 16;

  // stage W rows [h0*4, h0*4+64), cols [512,1536) into LDS (swizzled)
  for (int i = 0; i < 32; ++i) {
    const int chunk = i * 256 + t;          // 0..8191
    const int row = chunk >> 7;
    const int c16 = chunk & 127;
    const uint4 v = *(const uint4*)(Wcat + (size_t)(h0 * 4 + row) * EH + 512 + c16 * 8);
    *(uint4*)(Ws + row * 2048 + ((c16 * 16) ^ ((row & 7) << 4))) = v;
  }
  const int bl = t >> 4;                    // 0..15
  const int j  = t & 15;                    // hidden unit within slice
  const float4 bias = *(const float4*)(bias4 + (h0 + j) * 4);
  const int bg0 = grp * 32 + bl;
  const int bg1 = bg0 + 16;
  float cst0 = cstg[(size_t)bg0 * H_ + h0 + j];
  float cst1 = cstg[(size_t)bg1 * H_ + h0 + j];
  unsigned* flags = bar + grp * 64;         // 64 per-WG flag words
  const int rb = wid * 16 + (lane & 15);
  const char* wrow = Ws + rb * 2048;
  const int kq = (lane >> 4) * 8;
  const int swz = (rb & 7) << 4;
  __syncthreads();

  for (int s = 0; s < tc; ++s) {
    const int step = t0 + s;
    const bf16* aprev = (step & 1) ? a1 : a0;
    bf16* anext = (step & 1) ? a0 : a1;
    const bf16* gxrow = gx + (size_t)s * (B_ * G4);
    const bf16x4 g0 = *(const bf16x4*)(gxrow + (size_t)bg0 * G4 + (h0 + j) * 4);
    const bf16x4 g1 = *(const bf16x4*)(gxrow + (size_t)bg1 * G4 + (h0 + j) * 4);

    f32x4 acc0 = {0.f, 0.f, 0.f, 0.f}, acc1 = {0.f, 0.f, 0.f, 0.f};
    const bf16* ap0 = aprev + (size_t)(grp * 32 + (lane & 15)) * H_ + kq;
    const bf16* ap1 = ap0 + (size_t)16 * H_;
    #pragma unroll 4
    for (int k0 = 0; k0 < H_; k0 += 32) {
      const bf16x8 bfr = *(const bf16x8*)(wrow + (((k0 + kq) * 2) ^ swz));
      const bf16x8 af0 = *(const bf16x8*)(ap0 + k0);
      const bf16x8 af1 = *(const bf16x8*)(ap1 + k0);
      acc0 = __builtin_amdgcn_mfma_f32_16x16x32_bf16(af0, bfr, acc0, 0, 0, 0);
      acc1 = __builtin_amdgcn_mfma_f32_16x16x32_bf16(af1, bfr, acc1, 0, 0, 0);
    }
    {
      const int col = wid * 16 + (lane & 15);
      const int brow = (lane >> 4) * 4;
      #pragma unroll
      for (int r = 0; r < 4; ++r) {
        accs[(brow + r) * 64 + col]      = acc0[r];
        accs[(brow + r + 16) * 64 + col] = acc1[r];
      }
    }
    __syncthreads();
    const float4 p0 = *(const float4*)(accs + bl * 64 + j * 4);
    const float4 p1 = *(const float4*)(accs + (bl + 16) * 64 + j * 4);
    float hv0, hv1;
    {
      const float pf = p0.x + (float)g0[0] + bias.x;
      const float pi = p0.y + (float)g0[1] + bias.y;
      const float pc = p0.z + (float)g0[2] + bias.z;
      const float po = p0.w + (float)g0[3] + bias.w;
      const float fg = sigmoidf_(pf), ig = sigmoidf_(pi), og = sigmoidf_(po);
      cst0 = fg * cst0 + ig * tanh_fast(pc);
      hv0 = tanh_fast(cst0) * og;
    }
    {
      const float pf = p1.x + (float)g1[0] + bias.x;
      const float pi = p1.y + (float)g1[1] + bias.y;
      const float pc = p1.z + (float)g1[2] + bias.z;
      const float po = p1.w + (float)g1[3] + bias.w;
      const float fg = sigmoidf_(pf), ig = sigmoidf_(pi), og = sigmoidf_(po);
      cst1 = fg * cst1 + ig * tanh_fast(pc);
      hv1 = tanh_fast(cst1) * og;
    }
    // pack 2 bf16 per uint and publish write-through (relaxed, agent scope)
    {
      const unsigned u0 = (unsigned)__builtin_bit_cast(unsigned short, (bf16)hv0);
      const unsigned u1 = (unsigned)__builtin_bit_cast(unsigned short, (bf16)hv1);
      const unsigned n0 = __shfl_down(u0, 1);
      const unsigned n1 = __shfl_down(u1, 1);
      if ((j & 1) == 0) {
        unsigned* an = (unsigned*)anext;
        __hip_atomic_store(an + ((size_t)bg0 * H_ + h0 + j) / 2, u0 | (n0 << 16),
                           __ATOMIC_RELAXED, __HIP_MEMORY_SCOPE_AGENT);
        __hip_atomic_store(an + ((size_t)bg1 * H_ + h0 + j) / 2, u1 | (n1 << 16),
                           __ATOMIC_RELAXED, __HIP_MEMORY_SCOPE_AGENT);
      }
    }
    __syncthreads();   // drains each thread's stores (vmcnt 0) -> all at MALL
    if (t == 0) {
      __hip_atomic_store(flags + hwg, (unsigned)(step + 1),
                         __ATOMIC_RELAXED, __HIP_MEMORY_SCOPE_AGENT);
    }
    __builtin_amdgcn_sched_barrier(0);
    asm volatile("" ::: "memory");   // keep flag store above the poll
    if (t < 64) {
      unsigned v;
      do {
        v = __hip_atomic_load(flags + t, __ATOMIC_RELAXED, __HIP_MEMORY_SCOPE_AGENT);
      } while (v < (unsigned)(step + 1));
      __builtin_amdgcn_fence(__ATOMIC_ACQUIRE, "agent");  // buffer_inv: kill stale L2
    }
    __syncthreads();
  }
  cstg[(size_t)bg0 * H_ + h0 + j] = cst0;
  cstg[(size_t)bg1 * H_ + h0 + j] = cst1;
}

// ---- logits + per-batch loss ----
__global__ __launch_bounds__(256) void logits_loss(
    const bf16* __restrict__ afin, const float* __restrict__ Wv,
    const float* __restrict__ bv, const int* __restrict__ label,
    float* __restrict__ lossa)
{
  const int b = blockIdx.x;
  const int t = threadIdx.x;
  const int lane = t & 63, wid = t >> 6;
  const bf16x4 a4 = *(const bf16x4*)(afin + (size_t)b * H_ + t * 4);
  const float av0 = (float)a4[0], av1 = (float)a4[1], av2 = (float)a4[2], av3 = (float)a4[3];
  float part[C_];
  #pragma unroll
  for (int c = 0; c < C_; ++c) {
    const float4 w = *(const float4*)(Wv + (size_t)c * H_ + t * 4);
    part[c] = av0 * w.x + av1 * w.y + av2 * w.z + av3 * w.w;
  }
  #pragma unroll
  for (int off = 32; off > 0; off >>= 1) {
    #pragma unroll
    for (int c = 0; c < C_; ++c) part[c] += __shfl_down(part[c], off);
  }
  __shared__ float red[4][C_];
  __shared__ float lg[C_];
  if (lane == 0) {
    #pragma unroll
    for (int c = 0; c < C_; ++c) red[wid][c] = part[c];
  }
  __syncthreads();
  if (t < C_) lg[t] = red[0][t] + red[1][t] + red[2][t] + red[3][t] + bv[t];
  __syncthreads();
  if (t == 0) {
    float m = lg[0];
    for (int c = 1; c < C_; ++c) m = fmaxf(m, lg[c]);
    float se = 0.0f;
    for (int c = 0; c < C_; ++c) se += __expf(lg[c] - m);
    const float lse = logf(se) + m;
    lossa[b] = lse - lg[label[b]];
  }
}

__global__ __launch_bounds__(64) void loss_mean(const float* __restrict__ lossa,
                                                float* __restrict__ out) {
  const int t = threadIdx.x;
  float v = lossa[t];
  #pragma unroll
  for (int off = 32; off > 0; off >>= 1) v += __shfl_down(v, off);
  if (t == 0) out[0] = v * (1.0f / 64.0f);
}

extern "C" void kernel_launch(void* const* d_in, const int* in_sizes, int n_in,
                              void* d_out, int out_size, void* d_ws, size_t ws_size,
                              hipStream_t stream) {
  const int*   x     = (const int*)d_in[0];
  const int*   label = (const int*)d_in[1];
  const float* emb   = (const float*)d_in[2];
  const float* Wf    = (const float*)d_in[3];
  const float* bfp   = (const float*)d_in[4];
  const float* Wi    = (const float*)d_in[5];
  const float* bip   = (const float*)d_in[6];
  const float* Wc    = (const float*)d_in[7];
  const float* bcp   = (const float*)d_in[8];
  const float* Wo    = (const float*)d_in[9];
  const float* bop   = (const float*)d_in[10];
  const float* Wv    = (const float*)d_in[11];
  const float* bv    = (const float*)d_in[12];
  (void)in_sizes; (void)n_in; (void)out_size;

  // Pick the largest time-chunk TC whose gx buffer fits the workspace.
  int TC = 0;
  const size_t avail = (ws_size > OFF_GX) ? (ws_size - OFF_GX) : 0;
  const int cands[7] = {512, 256, 128, 64, 32, 16, 8};
  for (int i = 0; i < 7; ++i) {
    if ((size_t)cands[i] * 524288 <= avail) { TC = cands[i]; break; }
  }
  if (TC == 0) return;   // ws < ~17.3 MB — cannot run this design

  char* ws = (char*)d_ws;
  bf16*     Wcat  = (bf16*)(ws + OFF_WCAT);
  float*    bias4 = (float*)(ws + OFF_BIAS4);
  bf16*     a0    = (bf16*)(ws + OFF_A0);
  bf16*     a1    = (bf16*)(ws + OFF_A1);
  float*    cstg  = (float*)(ws + OFF_CST);
  float*    lossa = (float*)(ws + OFF_LOSS);
  unsigned* bar   = (unsigned*)(ws + OFF_BAR);
  bf16*     gx    = (bf16*)(ws + OFF_GX);

  init_misc<<<64, 256, 0, stream>>>((uint4*)(ws + OFF_A0));
  convert_w<<<1024, 256, 0, stream>>>(Wf, Wi, Wc, Wo, bfp, bip, bcp, bop, Wcat, bias4);
  hipFuncSetAttribute(reinterpret_cast<const void*>(lstm_rec),
                      hipFuncAttributeMaxDynamicSharedMemorySize, REC_LDS);
  const int nchunks = S_ / TC;
  for (int c = 0; c < nchunks; ++c) {
    const int t0 = c * TC;
    gemm_gx<<<(TC / 2) * 32, 256, 0, stream>>>(x, emb, Wcat, gx, t0);
    lstm_rec<<<128, 256, REC_LDS, stream>>>(Wcat, bias4, gx, a0, a1, cstg, bar, t0, TC);
  }
  logits_loss<<<64, 256, 0, stream>>>(a0, Wv, bv, label, lossa);
  loss_mean<<<1, 64, 0, stream>>>(lossa, (float*)d_out);
}

// Round 4
// 2723.323 us; speedup vs baseline: 6.5180x; 2.6526x over previous
//
#include <hip/hip_runtime.h>
#include <cstdint>
#include <cstddef>

typedef __bf16 bf16;
typedef __bf16 bf16x8 __attribute__((ext_vector_type(8)));
typedef __bf16 bf16x4 __attribute__((ext_vector_type(4)));
typedef float f32x4 __attribute__((ext_vector_type(4)));
typedef unsigned u32x4 __attribute__((ext_vector_type(4)));

#define B_ 64
#define S_ 512
#define E_ 512
#define H_ 1024
#define C_ 20
#define EH 1536   // E+H
#define G4 4096   // 4*H

// ---- workspace layout (bytes) ----
static const size_t OFF_WCAT  = 0;              // bf16 [4096][1536] = 12,582,912
static const size_t OFF_BIAS4 = 12582912;       // f32  [4096]       = 16,384
static const size_t OFF_A0    = 12599296;       // bf16 [64][1024]   = 131,072
static const size_t OFF_A1    = 12730368;       // bf16 [64][1024]   = 131,072
static const size_t OFF_CST   = 12861440;       // f32  [64][1024]   = 262,144
static const size_t OFF_LOSS  = 13123584;       // f32  [64]         = 256
static const size_t OFF_BAR   = 13123840;       // u32  [256]        = 1,024
static const size_t OFF_GX    = 13124864;       // bf16 [TC*64][4096] = TC*524,288
static const size_t STATE_BYTES = OFF_GX - OFF_A0;   // 525,568 (zeroed each call)

__device__ inline float sigmoidf_(float x) { return 1.0f / (1.0f + __expf(-x)); }
__device__ inline float tanh_fast(float x) {
  float ax = fabsf(x);
  float e = __expf(-2.0f * ax);
  float t = (1.0f - e) / (1.0f + e);
  return copysignf(t, x);
}

// coherent 16B load: bypass L1+L2, read the MALL coherence point directly.
// NOTE: result regs are NOT ready until a following s_waitcnt vmcnt.
__device__ inline void load_coh16(u32x4* dst, const void* p) {
  asm volatile("global_load_dwordx4 %0, %1, off sc0 sc1"
               : "=v"(*dst) : "v"(p) : "memory");
}

// ---- zero a0/a1/cst/loss/bar (state region is contiguous) ----
__global__ __launch_bounds__(256) void init_misc(uint4* st) {
  const int n = (int)(STATE_BYTES / 16);   // 32,848
  for (int idx = blockIdx.x * 256 + threadIdx.x; idx < n; idx += gridDim.x * 256)
    st[idx] = uint4{0u, 0u, 0u, 0u};
}

// ---- convert gate weights to bf16, rows r = h*4+g (h-major, gate minor) ----
__global__ __launch_bounds__(256) void convert_w(
    const float* __restrict__ Wf, const float* __restrict__ Wi,
    const float* __restrict__ Wc, const float* __restrict__ Wo,
    const float* __restrict__ bfp, const float* __restrict__ bip,
    const float* __restrict__ bcp, const float* __restrict__ bop,
    bf16* __restrict__ Wcat, float* __restrict__ bias4)
{
  const int total = G4 * (EH / 8);   // 786,432 chunks of 8
  for (int idx = blockIdx.x * 256 + threadIdx.x; idx < total; idx += gridDim.x * 256) {
    const int r = idx / 192;
    const int ck = idx - r * 192;
    const int g = r & 3, h = r >> 2;
    const float* W = (g == 0) ? Wf : (g == 1) ? Wi : (g == 2) ? Wc : Wo;
    const float* src = W + (size_t)h * EH + ck * 8;
    const float4 v0 = *(const float4*)src;
    const float4 v1 = *(const float4*)(src + 4);
    bf16x8 o;
    o[0] = (bf16)v0.x; o[1] = (bf16)v0.y; o[2] = (bf16)v0.z; o[3] = (bf16)v0.w;
    o[4] = (bf16)v1.x; o[5] = (bf16)v1.y; o[6] = (bf16)v1.z; o[7] = (bf16)v1.w;
    *(bf16x8*)(Wcat + (size_t)r * EH + ck * 8) = o;
    if (ck == 0) {
      const float* Bp = (g == 0) ? bfp : (g == 1) ? bip : (g == 2) ? bcp : bop;
      bias4[r] = Bp[h];
    }
  }
}

// ---- gx_chunk[ml][r] = sum_k emb[x[m]][k] * Wcat[r][k], K = 512 (x-part) ----
__global__ __launch_bounds__(256) void gemm_gx(
    const int* __restrict__ x, const float* __restrict__ emb,
    const bf16* __restrict__ Wcat, bf16* __restrict__ gx, int t0)
{
  __shared__ char As[16384];
  __shared__ char Bs[16384];
  const int t = threadIdx.x;
  const int lane = t & 63, wid = t >> 6;
  const int wm = wid >> 1, wn = wid & 1;
  const int bm = blockIdx.x >> 5;
  const int bn = blockIdx.x & 31;
  const int m0l = bm * 128, n0 = bn * 128;
  f32x4 acc[4][4] = {};
  const int srow = t >> 3, sc16 = t & 7;
  for (int k0 = 0; k0 < E_; k0 += 64) {
    __syncthreads();
    #pragma unroll
    for (int i = 0; i < 4; ++i) {
      const int row = i * 32 + srow;
      const int cs = sc16 ^ (row & 7);     // pre-swizzled source chunk
      const int m = t0 * 64 + m0l + row;
      const int tok = x[(m & 63) * S_ + (m >> 6)];
      const float* srcA = emb + (size_t)tok * E_ + k0 + cs * 8;
      const float4 a0v = *(const float4*)srcA;
      const float4 a1v = *(const float4*)(srcA + 4);
      bf16x8 oa;
      oa[0] = (bf16)a0v.x; oa[1] = (bf16)a0v.y; oa[2] = (bf16)a0v.z; oa[3] = (bf16)a0v.w;
      oa[4] = (bf16)a1v.x; oa[5] = (bf16)a1v.y; oa[6] = (bf16)a1v.z; oa[7] = (bf16)a1v.w;
      *(bf16x8*)(As + row * 128 + sc16 * 16) = oa;
      const uint4 vb = *(const uint4*)(Wcat + (size_t)(n0 + row) * EH + k0 + cs * 8);
      *(uint4*)(Bs + row * 128 + sc16 * 16) = vb;
    }
    __syncthreads();
    #pragma unroll
    for (int ks = 0; ks < 64; ks += 32) {
      const int kb = (ks + ((lane >> 4) * 8)) * 2;
      bf16x8 af[4], bfr[4];
      #pragma unroll
      for (int mt = 0; mt < 4; ++mt) {
        const int ra = wm * 64 + mt * 16 + (lane & 15);
        af[mt] = *(const bf16x8*)(As + ra * 128 + (kb ^ ((ra & 7) << 4)));
      }
      #pragma unroll
      for (int nt = 0; nt < 4; ++nt) {
        const int rb = wn * 64 + nt * 16 + (lane & 15);
        bfr[nt] = *(const bf16x8*)(Bs + rb * 128 + (kb ^ ((rb & 7) << 4)));
      }
      #pragma unroll
      for (int mt = 0; mt < 4; ++mt)
        #pragma unroll
        for (int nt = 0; nt < 4; ++nt)
          acc[mt][nt] = __builtin_amdgcn_mfma_f32_16x16x32_bf16(af[mt], bfr[nt], acc[mt][nt], 0, 0, 0);
    }
  }
  const int cb = (lane >> 4) * 4;
  #pragma unroll
  for (int mt = 0; mt < 4; ++mt) {
    #pragma unroll
    for (int r = 0; r < 4; ++r) {
      const int mrow = m0l + wm * 64 + mt * 16 + cb + r;   // chunk-local row
      bf16* dst = gx + (size_t)mrow * G4 + n0 + wn * 64 + (lane & 15);
      #pragma unroll
      for (int nt = 0; nt < 4; ++nt)
        dst[nt * 16] = (bf16)acc[mt][nt][r];
    }
  }
}

// ---- persistent LSTM recurrence over steps [t0, t0+tc) ----
// 256 WGs = 4 batch-groups (16 batches) x 64 hidden-slice WGs (16 h each).
// Per step: stage a_prev group-slice (16x1024 bf16 = 32 KB) into LDS via
// COHERENT loads (sc0 sc1 -> MALL, no fence/invalidate anywhere); MFMA
// [16 x 64] from LDS; gates; publish a_next via write-through agent stores;
// flag store; wave0 polls 64 flags in parallel. L2 is never invalidated.
// LDS: Ws 128 KB + union(a_tile 32 KB | accs 16x68 f32) = 160 KB exactly.
#define REC_LDS (131072 + 32768)
#define ACC_STRIDE 68

__global__ __launch_bounds__(256, 1) void lstm_rec(
    const bf16* __restrict__ Wcat, const float* __restrict__ bias4,
    const bf16* __restrict__ gx, bf16* __restrict__ a0,
    bf16* __restrict__ a1, float* __restrict__ cstg,
    unsigned* __restrict__ bar, int t0, int tc)
{
  extern __shared__ char smem[];
  char* Ws = smem;                          // [64][1024] bf16 swizzled
  char* AT = smem + 131072;                 // union: a_tile [16][1024] bf16 swz
  float* accs = (float*)(smem + 131072);    //        accs [16][68] f32
  const int t = threadIdx.x;
  const int lane = t & 63;
  const int wid = t >> 6;
  const int bid = blockIdx.x;
  const int grp = bid & 3;                  // batch group (16 batches)
  const int hwg = bid >> 2;                 // 0..63 hidden slice
  const int h0 = hwg * 16;

  // stage W rows [h0*4, h0*4+64), cols [512,1536) into LDS (swizzled)
  for (int i = 0; i < 32; ++i) {
    const int chunk = i * 256 + t;          // 0..8191
    const int row = chunk >> 7;
    const int c16 = chunk & 127;
    const uint4 v = *(const uint4*)(Wcat + (size_t)(h0 * 4 + row) * EH + 512 + c16 * 8);
    *(uint4*)(Ws + row * 2048 + ((c16 * 16) ^ ((row & 7) << 4))) = v;
  }
  const int bl = t >> 4;                    // 0..15 batch within group
  const int j  = t & 15;                    // hidden unit within slice
  const float4 bias = *(const float4*)(bias4 + (h0 + j) * 4);
  const int bg0 = grp * 16 + bl;
  float cst0 = cstg[(size_t)bg0 * H_ + h0 + j];
  unsigned* flags = bar + grp * 64;         // 64 per-WG flag words
  const int rb = wid * 16 + (lane & 15);
  const char* wrow = Ws + rb * 2048;
  const int kq = (lane >> 4) * 8;
  const int swz = (rb & 7) << 4;
  const int rowA = lane & 15;
  const char* arow = AT + rowA * 2048;
  const int swzA = (rowA & 7) << 4;
  // a-stage addressing: thread t stages chunks {i*2 + (t>>7)} row, col t&127
  const int sc16 = t & 127;
  const int srow0 = t >> 7;                 // 0 or 1
  __syncthreads();

  for (int s = 0; s < tc; ++s) {
    const int step = t0 + s;
    const bf16* aprev = (step & 1) ? a1 : a0;
    bf16* anext = (step & 1) ? a0 : a1;
    // --- stage a_prev[grp] slice into LDS via coherent loads ---
    const bf16* abase = aprev + (size_t)(grp * 16) * H_;
    u32x4 tmp[8];
    #pragma unroll
    for (int i = 0; i < 8; ++i) {
      const int row = srow0 + 2 * i;
      load_coh16(&tmp[i], abase + (size_t)row * H_ + sc16 * 8);
    }
    // gx for this step (plain load, issued early, consumed after MFMA)
    const bf16* gxrow = gx + (size_t)s * (B_ * G4);
    const bf16x4 g0 = *(const bf16x4*)(gxrow + (size_t)bg0 * G4 + (h0 + j) * 4);
    asm volatile("s_waitcnt vmcnt(0)" ::: "memory");
    __builtin_amdgcn_sched_barrier(0);
    #pragma unroll
    for (int i = 0; i < 8; ++i) {
      const int row = srow0 + 2 * i;
      *(u32x4*)(AT + row * 2048 + ((sc16 * 16) ^ ((row & 7) << 4))) = tmp[i];
    }
    __syncthreads();   // a_tile ready

    f32x4 acc0 = {0.f, 0.f, 0.f, 0.f};
    #pragma unroll 8
    for (int k0 = 0; k0 < H_; k0 += 32) {
      const int kb = (k0 + kq) * 2;
      const bf16x8 bfr = *(const bf16x8*)(wrow + (kb ^ swz));
      const bf16x8 af  = *(const bf16x8*)(arow + (kb ^ swzA));
      acc0 = __builtin_amdgcn_mfma_f32_16x16x32_bf16(af, bfr, acc0, 0, 0, 0);
    }
    __syncthreads();   // all a_tile reads done before accs overwrites union
    {
      const int col = wid * 16 + (lane & 15);
      const int brow = (lane >> 4) * 4;
      #pragma unroll
      for (int r = 0; r < 4; ++r)
        accs[(brow + r) * ACC_STRIDE + col] = acc0[r];
    }
    __syncthreads();
    const float4 p0 = *(const float4*)(accs + bl * ACC_STRIDE + j * 4);
    float hv0;
    {
      const float pf = p0.x + (float)g0[0] + bias.x;
      const float pi = p0.y + (float)g0[1] + bias.y;
      const float pc = p0.z + (float)g0[2] + bias.z;
      const float po = p0.w + (float)g0[3] + bias.w;
      const float fg = sigmoidf_(pf), ig = sigmoidf_(pi), og = sigmoidf_(po);
      cst0 = fg * cst0 + ig * tanh_fast(pc);
      hv0 = tanh_fast(cst0) * og;
    }
    // publish: pack 2 bf16 per dword, write-through agent store
    {
      const unsigned u0 = (unsigned)__builtin_bit_cast(unsigned short, (bf16)hv0);
      const unsigned n0 = __shfl_down(u0, 1);
      if ((j & 1) == 0) {
        unsigned* an = (unsigned*)anext;
        __hip_atomic_store(an + ((size_t)bg0 * H_ + h0 + j) / 2, u0 | (n0 << 16),
                           __ATOMIC_RELAXED, __HIP_MEMORY_SCOPE_AGENT);
      }
    }
    __syncthreads();   // drains all threads' stores (vmcnt 0) -> all at MALL
    if (t == 0) {
      __hip_atomic_store(flags + hwg, (unsigned)(step + 1),
                         __ATOMIC_RELAXED, __HIP_MEMORY_SCOPE_AGENT);
    }
    __builtin_amdgcn_sched_barrier(0);
    asm volatile("" ::: "memory");   // keep flag store above the poll
    if (t < 64) {
      unsigned v;
      do {
        v = __hip_atomic_load(flags + t, __ATOMIC_RELAXED, __HIP_MEMORY_SCOPE_AGENT);
      } while (v < (unsigned)(step + 1));
    }
    __syncthreads();   // no fence: consumers re-read via coherent loads only
  }
  cstg[(size_t)bg0 * H_ + h0 + j] = cst0;
}

// ---- logits + per-batch loss ----
__global__ __launch_bounds__(256) void logits_loss(
    const bf16* __restrict__ afin, const float* __restrict__ Wv,
    const float* __restrict__ bv, const int* __restrict__ label,
    float* __restrict__ lossa)
{
  const int b = blockIdx.x;
  const int t = threadIdx.x;
  const int lane = t & 63, wid = t >> 6;
  const bf16x4 a4 = *(const bf16x4*)(afin + (size_t)b * H_ + t * 4);
  const float av0 = (float)a4[0], av1 = (float)a4[1], av2 = (float)a4[2], av3 = (float)a4[3];
  float part[C_];
  #pragma unroll
  for (int c = 0; c < C_; ++c) {
    const float4 w = *(const float4*)(Wv + (size_t)c * H_ + t * 4);
    part[c] = av0 * w.x + av1 * w.y + av2 * w.z + av3 * w.w;
  }
  #pragma unroll
  for (int off = 32; off > 0; off >>= 1) {
    #pragma unroll
    for (int c = 0; c < C_; ++c) part[c] += __shfl_down(part[c], off);
  }
  __shared__ float red[4][C_];
  __shared__ float lg[C_];
  if (lane == 0) {
    #pragma unroll
    for (int c = 0; c < C_; ++c) red[wid][c] = part[c];
  }
  __syncthreads();
  if (t < C_) lg[t] = red[0][t] + red[1][t] + red[2][t] + red[3][t] + bv[t];
  __syncthreads();
  if (t == 0) {
    float m = lg[0];
    for (int c = 1; c < C_; ++c) m = fmaxf(m, lg[c]);
    float se = 0.0f;
    for (int c = 0; c < C_; ++c) se += __expf(lg[c] - m);
    const float lse = logf(se) + m;
    lossa[b] = lse - lg[label[b]];
  }
}

__global__ __launch_bounds__(64) void loss_mean(const float* __restrict__ lossa,
                                                float* __restrict__ out) {
  const int t = threadIdx.x;
  float v = lossa[t];
  #pragma unroll
  for (int off = 32; off > 0; off >>= 1) v += __shfl_down(v, off);
  if (t == 0) out[0] = v * (1.0f / 64.0f);
}

extern "C" void kernel_launch(void* const* d_in, const int* in_sizes, int n_in,
                              void* d_out, int out_size, void* d_ws, size_t ws_size,
                              hipStream_t stream) {
  const int*   x     = (const int*)d_in[0];
  const int*   label = (const int*)d_in[1];
  const float* emb   = (const float*)d_in[2];
  const float* Wf    = (const float*)d_in[3];
  const float* bfp   = (const float*)d_in[4];
  const float* Wi    = (const float*)d_in[5];
  const float* bip   = (const float*)d_in[6];
  const float* Wc    = (const float*)d_in[7];
  const float* bcp   = (const float*)d_in[8];
  const float* Wo    = (const float*)d_in[9];
  const float* bop   = (const float*)d_in[10];
  const float* Wv    = (const float*)d_in[11];
  const float* bv    = (const float*)d_in[12];
  (void)in_sizes; (void)n_in; (void)out_size;

  // Pick the largest time-chunk TC whose gx buffer fits the workspace.
  int TC = 0;
  const size_t avail = (ws_size > OFF_GX) ? (ws_size - OFF_GX) : 0;
  const int cands[7] = {512, 256, 128, 64, 32, 16, 8};
  for (int i = 0; i < 7; ++i) {
    if ((size_t)cands[i] * 524288 <= avail) { TC = cands[i]; break; }
  }
  if (TC == 0) return;   // ws < ~17.3 MB — cannot run this design

  char* ws = (char*)d_ws;
  bf16*     Wcat  = (bf16*)(ws + OFF_WCAT);
  float*    bias4 = (float*)(ws + OFF_BIAS4);
  bf16*     a0    = (bf16*)(ws + OFF_A0);
  bf16*     a1    = (bf16*)(ws + OFF_A1);
  float*    cstg  = (float*)(ws + OFF_CST);
  float*    lossa = (float*)(ws + OFF_LOSS);
  unsigned* bar   = (unsigned*)(ws + OFF_BAR);
  bf16*     gx    = (bf16*)(ws + OFF_GX);

  init_misc<<<64, 256, 0, stream>>>((uint4*)(ws + OFF_A0));
  convert_w<<<1024, 256, 0, stream>>>(Wf, Wi, Wc, Wo, bfp, bip, bcp, bop, Wcat, bias4);
  hipFuncSetAttribute(reinterpret_cast<const void*>(lstm_rec),
                      hipFuncAttributeMaxDynamicSharedMemorySize, REC_LDS);
  const int nchunks = S_ / TC;
  for (int c = 0; c < nchunks; ++c) {
    const int t0 = c * TC;
    gemm_gx<<<(TC / 2) * 32, 256, 0, stream>>>(x, emb, Wcat, gx, t0);
    lstm_rec<<<256, 256, REC_LDS, stream>>>(Wcat, bias4, gx, a0, a1, cstg, bar, t0, TC);
  }
  logits_loss<<<64, 256, 0, stream>>>(a0, Wv, bv, label, lossa);
  loss_mean<<<1, 64, 0, stream>>>(lossa, (float*)d_out);
}

// Round 5
// 2121.632 us; speedup vs baseline: 8.3664x; 1.2836x over previous
//
#include <hip/hip_runtime.h>
#include <cstdint>
#include <cstddef>

typedef __bf16 bf16;
typedef __bf16 bf16x8 __attribute__((ext_vector_type(8)));
typedef __bf16 bf16x4 __attribute__((ext_vector_type(4)));
typedef float f32x4 __attribute__((ext_vector_type(4)));
typedef unsigned u32x4 __attribute__((ext_vector_type(4)));

#define B_ 64
#define S_ 512
#define E_ 512
#define H_ 1024
#define C_ 20
#define EH 1536   // E+H
#define G4 4096   // 4*H

// ---- workspace layout (bytes) ----
static const size_t OFF_WCAT  = 0;              // bf16 [4096][1536] = 12,582,912
static const size_t OFF_BIAS4 = 12582912;       // f32  [4096]       = 16,384
static const size_t OFF_A0    = 12599296;       // bf16 [64][1024]   = 131,072
static const size_t OFF_A1    = 12730368;       // bf16 [64][1024]   = 131,072
static const size_t OFF_CST   = 12861440;       // f32  [64][1024]   = 262,144
static const size_t OFF_LOSS  = 13123584;       // f32  [64]         = 256
static const size_t OFF_BAR   = 13123840;       // u32  [256]        = 1,024
static const size_t OFF_GX    = 13124864;       // bf16 [TC*64][4096] = TC*524,288
static const size_t STATE_BYTES = OFF_GX - OFF_A0;   // 525,568 (zeroed each call)

__device__ inline float sigmoidf_(float x) { return 1.0f / (1.0f + __expf(-x)); }
__device__ inline float tanh_fast(float x) {
  float ax = fabsf(x);
  float e = __expf(-2.0f * ax);
  float t = (1.0f - e) / (1.0f + e);
  return copysignf(t, x);
}

// coherent 16B load: bypass L1+L2, read the MALL coherence point directly.
// NOTE: result regs are NOT ready until a following s_waitcnt vmcnt.
__device__ inline void load_coh16(u32x4* dst, const void* p) {
  asm volatile("global_load_dwordx4 %0, %1, off sc0 sc1"
               : "=v"(*dst) : "v"(p) : "memory");
}

// ---- zero a0/a1/cst/loss/bar (state region is contiguous) ----
__global__ __launch_bounds__(256) void init_misc(uint4* st) {
  const int n = (int)(STATE_BYTES / 16);   // 32,848
  for (int idx = blockIdx.x * 256 + threadIdx.x; idx < n; idx += gridDim.x * 256)
    st[idx] = uint4{0u, 0u, 0u, 0u};
}

// ---- convert gate weights to bf16, rows r = h*4+g (h-major, gate minor) ----
__global__ __launch_bounds__(256) void convert_w(
    const float* __restrict__ Wf, const float* __restrict__ Wi,
    const float* __restrict__ Wc, const float* __restrict__ Wo,
    const float* __restrict__ bfp, const float* __restrict__ bip,
    const float* __restrict__ bcp, const float* __restrict__ bop,
    bf16* __restrict__ Wcat, float* __restrict__ bias4)
{
  const int total = G4 * (EH / 8);   // 786,432 chunks of 8
  for (int idx = blockIdx.x * 256 + threadIdx.x; idx < total; idx += gridDim.x * 256) {
    const int r = idx / 192;
    const int ck = idx - r * 192;
    const int g = r & 3, h = r >> 2;
    const float* W = (g == 0) ? Wf : (g == 1) ? Wi : (g == 2) ? Wc : Wo;
    const float* src = W + (size_t)h * EH + ck * 8;
    const float4 v0 = *(const float4*)src;
    const float4 v1 = *(const float4*)(src + 4);
    bf16x8 o;
    o[0] = (bf16)v0.x; o[1] = (bf16)v0.y; o[2] = (bf16)v0.z; o[3] = (bf16)v0.w;
    o[4] = (bf16)v1.x; o[5] = (bf16)v1.y; o[6] = (bf16)v1.z; o[7] = (bf16)v1.w;
    *(bf16x8*)(Wcat + (size_t)r * EH + ck * 8) = o;
    if (ck == 0) {
      const float* Bp = (g == 0) ? bfp : (g == 1) ? bip : (g == 2) ? bcp : bop;
      bias4[r] = Bp[h];
    }
  }
}

// ---- gx_chunk[ml][r] = sum_k emb[x[m]][k] * Wcat[r][k], K = 512 (x-part) ----
__global__ __launch_bounds__(256) void gemm_gx(
    const int* __restrict__ x, const float* __restrict__ emb,
    const bf16* __restrict__ Wcat, bf16* __restrict__ gx, int t0)
{
  __shared__ char As[16384];
  __shared__ char Bs[16384];
  const int t = threadIdx.x;
  const int lane = t & 63, wid = t >> 6;
  const int wm = wid >> 1, wn = wid & 1;
  const int bm = blockIdx.x >> 5;
  const int bn = blockIdx.x & 31;
  const int m0l = bm * 128, n0 = bn * 128;
  f32x4 acc[4][4] = {};
  const int srow = t >> 3, sc16 = t & 7;
  for (int k0 = 0; k0 < E_; k0 += 64) {
    __syncthreads();
    #pragma unroll
    for (int i = 0; i < 4; ++i) {
      const int row = i * 32 + srow;
      const int cs = sc16 ^ (row & 7);     // pre-swizzled source chunk
      const int m = t0 * 64 + m0l + row;
      const int tok = x[(m & 63) * S_ + (m >> 6)];
      const float* srcA = emb + (size_t)tok * E_ + k0 + cs * 8;
      const float4 a0v = *(const float4*)srcA;
      const float4 a1v = *(const float4*)(srcA + 4);
      bf16x8 oa;
      oa[0] = (bf16)a0v.x; oa[1] = (bf16)a0v.y; oa[2] = (bf16)a0v.z; oa[3] = (bf16)a0v.w;
      oa[4] = (bf16)a1v.x; oa[5] = (bf16)a1v.y; oa[6] = (bf16)a1v.z; oa[7] = (bf16)a1v.w;
      *(bf16x8*)(As + row * 128 + sc16 * 16) = oa;
      const uint4 vb = *(const uint4*)(Wcat + (size_t)(n0 + row) * EH + k0 + cs * 8);
      *(uint4*)(Bs + row * 128 + sc16 * 16) = vb;
    }
    __syncthreads();
    #pragma unroll
    for (int ks = 0; ks < 64; ks += 32) {
      const int kb = (ks + ((lane >> 4) * 8)) * 2;
      bf16x8 af[4], bfr[4];
      #pragma unroll
      for (int mt = 0; mt < 4; ++mt) {
        const int ra = wm * 64 + mt * 16 + (lane & 15);
        af[mt] = *(const bf16x8*)(As + ra * 128 + (kb ^ ((ra & 7) << 4)));
      }
      #pragma unroll
      for (int nt = 0; nt < 4; ++nt) {
        const int rb = wn * 64 + nt * 16 + (lane & 15);
        bfr[nt] = *(const bf16x8*)(Bs + rb * 128 + (kb ^ ((rb & 7) << 4)));
      }
      #pragma unroll
      for (int mt = 0; mt < 4; ++mt)
        #pragma unroll
        for (int nt = 0; nt < 4; ++nt)
          acc[mt][nt] = __builtin_amdgcn_mfma_f32_16x16x32_bf16(af[mt], bfr[nt], acc[mt][nt], 0, 0, 0);
    }
  }
  const int cb = (lane >> 4) * 4;
  #pragma unroll
  for (int mt = 0; mt < 4; ++mt) {
    #pragma unroll
    for (int r = 0; r < 4; ++r) {
      const int mrow = m0l + wm * 64 + mt * 16 + cb + r;   // chunk-local row
      bf16* dst = gx + (size_t)mrow * G4 + n0 + wn * 64 + (lane & 15);
      #pragma unroll
      for (int nt = 0; nt < 4; ++nt)
        dst[nt * 16] = (bf16)acc[mt][nt][r];
    }
  }
}

// ---- persistent LSTM recurrence over steps [t0, t0+tc) ----
// 256 WGs = 4 batch-groups (16 batches) x 64 hidden-slice WGs (16 h each).
// R5: no LDS on the critical path. Wave w owns K-quarter [256w,256w+256):
//   - W B-fragments for all 64 gate rows of this WG preloaded to 128 VGPRs.
//   - A-fragments loaded per step directly via coherent 16B loads (no LDS).
//   - wave polls only ITS 16 producer flags (fine-grained start, skew absorb);
//     WG-level publish still gates on all 64 via the 4 waves' union.
// LDS: only accs[4][16][68] f32 (17.4 KB) for the cross-wave K-reduction.
__global__ __launch_bounds__(256, 1) void lstm_rec(
    const bf16* __restrict__ Wcat, const float* __restrict__ bias4,
    const bf16* __restrict__ gx, bf16* __restrict__ a0,
    bf16* __restrict__ a1, float* __restrict__ cstg,
    unsigned* __restrict__ bar, int t0, int tc)
{
  __shared__ float accs[4][16][68];
  const int t = threadIdx.x;
  const int lane = t & 63;
  const int w = t >> 6;                     // wave id = K-quarter
  const int bid = blockIdx.x;
  const int grp = bid & 3;                  // batch group (16 batches)
  const int hwg = bid >> 2;                 // 0..63 hidden slice
  const int h0 = hwg * 16;
  const int l15 = lane & 15;
  const int kq = (lane >> 4) * 8;           // k sub-offset within a 32-chunk

  // --- preload W B-fragments: 64 gate rows x my K-quarter (256 cols) ---
  bf16x8 wf[32];                            // [nt*8 + i], static-indexed
  {
    const bf16* wbase = Wcat + (size_t)(h0 * 4 + l15) * EH + 512 + w * 256 + kq;
    #pragma unroll
    for (int nt = 0; nt < 4; ++nt)
      #pragma unroll
      for (int i = 0; i < 8; ++i)
        wf[nt * 8 + i] = *(const bf16x8*)(wbase + (size_t)nt * 16 * EH + i * 32);
  }
  const int j   = t & 15;                   // hidden unit within slice
  const int blb = t >> 4;                   // batch within group (reduce phase)
  const float4 bias = *(const float4*)(bias4 + (h0 + j) * 4);
  const int bg0 = grp * 16 + blb;
  float cst = cstg[(size_t)bg0 * H_ + h0 + j];
  unsigned* flags = bar + grp * 64;         // 64 per-WG flag words
  unsigned* myflag = flags + w * 16 + l15;  // this lane's producer flag

  for (int s = 0; s < tc; ++s) {
    const int step = t0 + s;
    const bf16* aprev = (step & 1) ? a1 : a0;
    bf16* anext = (step & 1) ? a0 : a1;
    // gx for this step: chunk-static, load BEFORE the poll (overlapped)
    const bf16* gxrow = gx + (size_t)s * (B_ * G4);
    const bf16x4 g0 = *(const bf16x4*)(gxrow + (size_t)bg0 * G4 + (h0 + j) * 4);
    // wave-level poll: only my K-quarter's 16 producers must have published
    {
      unsigned v;
      do {
        v = __hip_atomic_load(myflag, __ATOMIC_RELAXED, __HIP_MEMORY_SCOPE_AGENT);
      } while (v < (unsigned)step);
    }
    __builtin_amdgcn_sched_barrier(0);
    // A-fragments straight from MALL: lane = batch l15, cols quarter+kq
    const bf16* abase = aprev + (size_t)(grp * 16 + l15) * H_ + w * 256 + kq;
    u32x4 af[8];
    #pragma unroll
    for (int i = 0; i < 8; ++i) load_coh16(&af[i], abase + i * 32);
    asm volatile("s_waitcnt vmcnt(0)" ::: "memory");
    __builtin_amdgcn_sched_barrier(0);
    f32x4 pacc[4] = {};
    #pragma unroll
    for (int i = 0; i < 8; ++i) {
      const bf16x8 a8 = __builtin_bit_cast(bf16x8, af[i]);
      #pragma unroll
      for (int nt = 0; nt < 4; ++nt)
        pacc[nt] = __builtin_amdgcn_mfma_f32_16x16x32_bf16(a8, wf[nt * 8 + i], pacc[nt], 0, 0, 0);
    }
    __syncthreads();   // WAR: all waves done reading prev step's accs
    {
      const int m0 = (lane >> 4) * 4;
      #pragma unroll
      for (int nt = 0; nt < 4; ++nt)
        #pragma unroll
        for (int r = 0; r < 4; ++r)
          accs[w][m0 + r][nt * 16 + l15] = pacc[nt][r];
    }
    __syncthreads();
    // reduce the 4 K-partials for (batch blb, h-unit j): 4 gate pre-acts
    const float4 q0 = *(const float4*)&accs[0][blb][j * 4];
    const float4 q1 = *(const float4*)&accs[1][blb][j * 4];
    const float4 q2 = *(const float4*)&accs[2][blb][j * 4];
    const float4 q3 = *(const float4*)&accs[3][blb][j * 4];
    float hv;
    {
      const float pf = q0.x + q1.x + q2.x + q3.x + (float)g0[0] + bias.x;
      const float pi = q0.y + q1.y + q2.y + q3.y + (float)g0[1] + bias.y;
      const float pc = q0.z + q1.z + q2.z + q3.z + (float)g0[2] + bias.z;
      const float po = q0.w + q1.w + q2.w + q3.w + (float)g0[3] + bias.w;
      const float fg = sigmoidf_(pf), ig = sigmoidf_(pi), og = sigmoidf_(po);
      cst = fg * cst + ig * tanh_fast(pc);
      hv = tanh_fast(cst) * og;
    }
    // publish: pack 2 bf16 per dword, write-through agent store
    {
      const unsigned u0 = (unsigned)__builtin_bit_cast(unsigned short, (bf16)hv);
      const unsigned n0 = __shfl_down(u0, 1);
      if ((j & 1) == 0) {
        unsigned* an = (unsigned*)anext;
        __hip_atomic_store(an + ((size_t)bg0 * H_ + h0 + j) / 2, u0 | (n0 << 16),
                           __ATOMIC_RELAXED, __HIP_MEMORY_SCOPE_AGENT);
      }
    }
    __syncthreads();   // drains all threads' stores (vmcnt 0) -> all at MALL
    if (t == 0) {
      __hip_atomic_store(flags + hwg, (unsigned)(step + 1),
                         __ATOMIC_RELAXED, __HIP_MEMORY_SCOPE_AGENT);
    }
  }
  cstg[(size_t)bg0 * H_ + h0 + j] = cst;
}

// ---- logits + per-batch loss ----
__global__ __launch_bounds__(256) void logits_loss(
    const bf16* __restrict__ afin, const float* __restrict__ Wv,
    const float* __restrict__ bv, const int* __restrict__ label,
    float* __restrict__ lossa)
{
  const int b = blockIdx.x;
  const int t = threadIdx.x;
  const int lane = t & 63, wid = t >> 6;
  const bf16x4 a4 = *(const bf16x4*)(afin + (size_t)b * H_ + t * 4);
  const float av0 = (float)a4[0], av1 = (float)a4[1], av2 = (float)a4[2], av3 = (float)a4[3];
  float part[C_];
  #pragma unroll
  for (int c = 0; c < C_; ++c) {
    const float4 w = *(const float4*)(Wv + (size_t)c * H_ + t * 4);
    part[c] = av0 * w.x + av1 * w.y + av2 * w.z + av3 * w.w;
  }
  #pragma unroll
  for (int off = 32; off > 0; off >>= 1) {
    #pragma unroll
    for (int c = 0; c < C_; ++c) part[c] += __shfl_down(part[c], off);
  }
  __shared__ float red[4][C_];
  __shared__ float lg[C_];
  if (lane == 0) {
    #pragma unroll
    for (int c = 0; c < C_; ++c) red[wid][c] = part[c];
  }
  __syncthreads();
  if (t < C_) lg[t] = red[0][t] + red[1][t] + red[2][t] + red[3][t] + bv[t];
  __syncthreads();
  if (t == 0) {
    float m = lg[0];
    for (int c = 1; c < C_; ++c) m = fmaxf(m, lg[c]);
    float se = 0.0f;
    for (int c = 0; c < C_; ++c) se += __expf(lg[c] - m);
    const float lse = logf(se) + m;
    lossa[b] = lse - lg[label[b]];
  }
}

__global__ __launch_bounds__(64) void loss_mean(const float* __restrict__ lossa,
                                                float* __restrict__ out) {
  const int t = threadIdx.x;
  float v = lossa[t];
  #pragma unroll
  for (int off = 32; off > 0; off >>= 1) v += __shfl_down(v, off);
  if (t == 0) out[0] = v * (1.0f / 64.0f);
}

extern "C" void kernel_launch(void* const* d_in, const int* in_sizes, int n_in,
                              void* d_out, int out_size, void* d_ws, size_t ws_size,
                              hipStream_t stream) {
  const int*   x     = (const int*)d_in[0];
  const int*   label = (const int*)d_in[1];
  const float* emb   = (const float*)d_in[2];
  const float* Wf    = (const float*)d_in[3];
  const float* bfp   = (const float*)d_in[4];
  const float* Wi    = (const float*)d_in[5];
  const float* bip   = (const float*)d_in[6];
  const float* Wc    = (const float*)d_in[7];
  const float* bcp   = (const float*)d_in[8];
  const float* Wo    = (const float*)d_in[9];
  const float* bop   = (const float*)d_in[10];
  const float* Wv    = (const float*)d_in[11];
  const float* bv    = (const float*)d_in[12];
  (void)in_sizes; (void)n_in; (void)out_size;

  // Pick the largest time-chunk TC whose gx buffer fits the workspace.
  int TC = 0;
  const size_t avail = (ws_size > OFF_GX) ? (ws_size - OFF_GX) : 0;
  const int cands[7] = {512, 256, 128, 64, 32, 16, 8};
  for (int i = 0; i < 7; ++i) {
    if ((size_t)cands[i] * 524288 <= avail) { TC = cands[i]; break; }
  }
  if (TC == 0) return;   // ws < ~17.3 MB — cannot run this design

  char* ws = (char*)d_ws;
  bf16*     Wcat  = (bf16*)(ws + OFF_WCAT);
  float*    bias4 = (float*)(ws + OFF_BIAS4);
  bf16*     a0    = (bf16*)(ws + OFF_A0);
  bf16*     a1    = (bf16*)(ws + OFF_A1);
  float*    cstg  = (float*)(ws + OFF_CST);
  float*    lossa = (float*)(ws + OFF_LOSS);
  unsigned* bar   = (unsigned*)(ws + OFF_BAR);
  bf16*     gx    = (bf16*)(ws + OFF_GX);

  init_misc<<<64, 256, 0, stream>>>((uint4*)(ws + OFF_A0));
  convert_w<<<1024, 256, 0, stream>>>(Wf, Wi, Wc, Wo, bfp, bip, bcp, bop, Wcat, bias4);
  const int nchunks = S_ / TC;
  for (int c = 0; c < nchunks; ++c) {
    const int t0 = c * TC;
    gemm_gx<<<(TC / 2) * 32, 256, 0, stream>>>(x, emb, Wcat, gx, t0);
    lstm_rec<<<256, 256, 0, stream>>>(Wcat, bias4, gx, a0, a1, cstg, bar, t0, TC);
  }
  logits_loss<<<64, 256, 0, stream>>>(a0, Wv, bv, label, lossa);
  loss_mean<<<1, 64, 0, stream>>>(lossa, (float*)d_out);
}